// Round 7
// baseline (106.321 us; speedup 1.0000x reference)
//
#include <hip/hip_runtime.h>

#define N_ 1024
#define M_ 1024
#define D_ 128
#define NNZ_ 32768
#define H_ 256

typedef _Float16 h2 __attribute__((ext_vector_type(2)));

// ---- K1: 256 blocks x 512 threads (1 block/CU, 2 waves/SIMD).
// Stage A (B0->B1): waves 0-3: hx rows [4b,4b+4) = X @ W1[:D]  (reg-resident)
//                   waves 4-7: E-scan -> LDS buckets (V loaded only on hit)
// Stage B (B1->B2): waves 0-3 store hx; ALL 512 threads build segment sums
//                   (one (row,d) pair per thread).
// Stage C (B2-> ) : ALL 512 threads heb GEMM (rows split 2/2 across halves).
// Round-7 deltas (latency batching, order-preserving):
//   scan unroll 4->8 (8 E4 loads in flight; scan is L2-latency-bound),
//   dd-loops unroll 2 (8 W-column loads in flight).
__global__ __launch_bounds__(512) void gemm_kernel(
        const float* __restrict__ X, const int* __restrict__ V,
        const int* __restrict__ E, const float* __restrict__ W1,
        const float* __restrict__ b1,
        _Float16* __restrict__ hx, _Float16* __restrict__ heb) {
    __shared__ float sA[8][128];       // rows 0-3: X rows; rows 4-7: segment sums
    __shared__ int s_bkt[4][128];      // bucket (cap 128; counts ~Poisson(32))
    __shared__ int s_cnt[4];
    const int t = threadIdx.x;
    const int b = blockIdx.x;
    const int row0 = b * 4;
    const int m0 = b * 4;
    const int u = t & 255;

    if (t < 128)
        ((float4*)&sA[0][0])[t] = ((const float4*)(X + row0 * D_))[t];
    if (t >= 256 && t < 260) s_cnt[t - 256] = 0;
    __syncthreads();   // B0

    float acc[4];
#pragma unroll
    for (int r = 0; r < 4; ++r) acc[r] = 0.f;

    // ---------- stage A: top GEMM || bottom E-scan ----------
    if (t < 256) {
        const float* __restrict__ Wa = W1;
#pragma unroll 2
        for (int dd = 0; dd < D_; dd += 4) {
            float w0 = Wa[(dd + 0) * H_ + t];
            float w1 = Wa[(dd + 1) * H_ + t];
            float w2 = Wa[(dd + 2) * H_ + t];
            float w3 = Wa[(dd + 3) * H_ + t];
#pragma unroll
            for (int r = 0; r < 4; ++r) {
                float4 a = *(const float4*)&sA[r][dd];
                acc[r] = fmaf(a.x, w0, acc[r]);
                acc[r] = fmaf(a.y, w1, acc[r]);
                acc[r] = fmaf(a.z, w2, acc[r]);
                acc[r] = fmaf(a.w, w3, acc[r]);
            }
        }
    } else {
        const int4* E4 = (const int4*)E;
        const int4* V4 = (const int4*)V;
#pragma unroll 8
        for (int it = 0; it < NNZ_ / 4 / 256; ++it) {   // 32 iters
            int idx = it * 256 + u;
            int4 e4 = E4[idx];
            unsigned r0 = (unsigned)(e4.x - m0);
            unsigned r1 = (unsigned)(e4.y - m0);
            unsigned r2 = (unsigned)(e4.z - m0);
            unsigned r3 = (unsigned)(e4.w - m0);
            if ((r0 < 4u) | (r1 < 4u) | (r2 < 4u) | (r3 < 4u)) {
                int4 v4 = V4[idx];
                if (r0 < 4u) { int s = atomicAdd(&s_cnt[r0], 1); s_bkt[r0][s & 127] = v4.x; }
                if (r1 < 4u) { int s = atomicAdd(&s_cnt[r1], 1); s_bkt[r1][s & 127] = v4.y; }
                if (r2 < 4u) { int s = atomicAdd(&s_cnt[r2], 1); s_bkt[r2][s & 127] = v4.z; }
                if (r3 < 4u) { int s = atomicAdd(&s_cnt[r3], 1); s_bkt[r3][s & 127] = v4.w; }
            }
        }
    }
    __syncthreads();   // B1: buckets complete

    // ---------- stage B: hx store, then all-thread segment sums ----------
    if (t < 256) {
#pragma unroll
        for (int r = 0; r < 4; ++r)
            hx[(row0 + r) * H_ + t] = (_Float16)acc[r];
    }
    {
        const int d = t & 127;
        const int r = t >> 7;          // 0..3 — one (row, d) per thread
        const int cnt = min(s_cnt[r], 128);
        float s = 0.f;
        int i = 0;
        for (; i + 8 <= cnt; i += 8) {  // 8 outstanding loads (latency-bound)
            int v0 = s_bkt[r][i],     v1 = s_bkt[r][i + 1];
            int v2 = s_bkt[r][i + 2], v3 = s_bkt[r][i + 3];
            int v4 = s_bkt[r][i + 4], v5 = s_bkt[r][i + 5];
            int v6 = s_bkt[r][i + 6], v7 = s_bkt[r][i + 7];
            s += X[v0 * D_ + d];
            s += X[v1 * D_ + d];
            s += X[v2 * D_ + d];
            s += X[v3 * D_ + d];
            s += X[v4 * D_ + d];
            s += X[v5 * D_ + d];
            s += X[v6 * D_ + d];
            s += X[v7 * D_ + d];
        }
        for (; i + 4 <= cnt; i += 4) {
            int v0 = s_bkt[r][i],     v1 = s_bkt[r][i + 1];
            int v2 = s_bkt[r][i + 2], v3 = s_bkt[r][i + 3];
            s += X[v0 * D_ + d];
            s += X[v1 * D_ + d];
            s += X[v2 * D_ + d];
            s += X[v3 * D_ + d];
        }
        for (; i < cnt; ++i) s += X[s_bkt[r][i] * D_ + d];
        sA[4 + r][d] = s;
    }
    __syncthreads();   // B2: sums visible

    // ---------- stage C: all-thread heb GEMM (rows split 2/2) ----------
    {
        const int rbase = (t < 256) ? 0 : 2;   // rows rbase, rbase+1
        float acc2[2];
        acc2[0] = 0.f;
        acc2[1] = 0.f;
        const float* __restrict__ Wb = W1 + D_ * H_;
#pragma unroll 2
        for (int dd = 0; dd < D_; dd += 4) {
            float w0 = Wb[(dd + 0) * H_ + u];
            float w1 = Wb[(dd + 1) * H_ + u];
            float w2 = Wb[(dd + 2) * H_ + u];
            float w3 = Wb[(dd + 3) * H_ + u];
#pragma unroll
            for (int r = 0; r < 2; ++r) {
                float4 a = *(const float4*)&sA[4 + rbase + r][dd];
                acc2[r] = fmaf(a.x, w0, acc2[r]);
                acc2[r] = fmaf(a.y, w1, acc2[r]);
                acc2[r] = fmaf(a.z, w2, acc2[r]);
                acc2[r] = fmaf(a.w, w3, acc2[r]);
            }
        }
        const float bias = b1[u];
#pragma unroll
        for (int r = 0; r < 2; ++r) {
            float inv = 1.0f / fmaxf((float)s_cnt[rbase + r], 1.0f);
            heb[(m0 + rbase + r) * H_ + u] = (_Float16)(acc2[r] * inv + bias);
        }
    }
}

// ---- K2: out[n,m] = sigmoid(b2 + sum_h relu(hx[n,h]+heb[m,h]) * W2[h])
// 64x64 tile / block, 512 threads (2 waves/SIMD), 2x4 per thread.
// Round-7 delta: H split into two 128-half chunks, double-buffered through
// registers — global loads for BOTH halves issue up front; half-1's latency
// hides under half-0's ~2.5 us of compute (was: serial 64 KB stage + barrier).
// Accumulation order identical to single-loop version (h0 chunks then h1).
// Row stride 136 halves = 272 B = 68 words (mod 32 = 4): bv b128 reads are
// 2-way bank-aliased (free), av reads broadcast. Inner loop VALU-bound at
// 3 instr / 2 h, ~5.1 us packed-VALU floor.
// (Closed paths: round-1 4x4/256t retile (-4 us, occupancy); round-3
// cooperative fusion (-88 us, grid.sync stall).)
__global__ __launch_bounds__(512) void big_kernel(
        const _Float16* __restrict__ hx, const _Float16* __restrict__ heb,
        const float* __restrict__ W2, const float* __restrict__ b2,
        float* __restrict__ out) {
    __shared__ _Float16 sA[2][64][136];   // 2 halves x 64 rows x 128(+8 pad)
    __shared__ _Float16 sB[2][64][136];   // 34 KB each; total ~70 KB
    __shared__ h2 sW[H_ / 2];

    const int tid = threadIdx.x;
    const int tx = tid & 15;          // m
    const int ty = tid >> 4;          // n, 0..31
    const int n0 = blockIdx.y * 64;
    const int m0 = blockIdx.x * 64;

    if (tid < H_ / 2) {
        h2 w;
        w.x = (_Float16)W2[2 * tid];
        w.y = (_Float16)W2[2 * tid + 1];
        sW[tid] = w;
    }

    // issue ALL global loads (h0 then h1); h1 stays in flight through h0 compute
    const float4* A4 = (const float4*)hx;   // 32 float4 per 256-half row
    const float4* B4 = (const float4*)heb;
    float4 ra0[2], rb0[2], ra1[2], rb1[2];
#pragma unroll
    for (int it = 0; it < 2; ++it) {        // half 0: float4 cols 0..15
        int lin = it * 512 + tid;
        int row = lin >> 4, c = lin & 15;
        ra0[it] = A4[(n0 + row) * 32 + c];
        rb0[it] = B4[(m0 + row) * 32 + c];
    }
#pragma unroll
    for (int it = 0; it < 2; ++it) {        // half 1: float4 cols 16..31
        int lin = it * 512 + tid;
        int row = lin >> 4, c = lin & 15;
        ra1[it] = A4[(n0 + row) * 32 + 16 + c];
        rb1[it] = B4[(m0 + row) * 32 + 16 + c];
    }
#pragma unroll
    for (int it = 0; it < 2; ++it) {        // LDS-write half 0 (waits vmcnt(4))
        int lin = it * 512 + tid;
        int row = lin >> 4, c = lin & 15;
        *(float4*)&sA[0][row][c * 8] = ra0[it];
        *(float4*)&sB[0][row][c * 8] = rb0[it];
    }
    __syncthreads();

    float acc[2][4];
#pragma unroll
    for (int i = 0; i < 2; ++i)
#pragma unroll
        for (int j = 0; j < 4; ++j) acc[i][j] = 0.f;

    union Vn { float4 f4; h2 h[4]; };
    const h2 z = {(_Float16)0.f, (_Float16)0.f};

    // ---- half 0 compute (h1 global loads still in flight) ----
#pragma unroll 4
    for (int hp = 0; hp < 64; hp += 4) {
        Vn av[2], bv[4], wv;
        wv.f4 = *(const float4*)&sW[hp];
#pragma unroll
        for (int i = 0; i < 2; ++i) av[i].f4 = *(const float4*)&sA[0][ty + 32 * i][hp * 2];
#pragma unroll
        for (int j = 0; j < 4; ++j) bv[j].f4 = *(const float4*)&sB[0][tx + 16 * j][hp * 2];
#pragma unroll
        for (int k = 0; k < 4; ++k) {
#pragma unroll
            for (int i = 0; i < 2; ++i) {
#pragma unroll
                for (int j = 0; j < 4; ++j) {
                    h2 s = av[i].h[k] + bv[j].h[k];
                    s = __builtin_elementwise_max(s, z);
                    acc[i][j] = __builtin_amdgcn_fdot2(s, wv.h[k], acc[i][j], false);
                }
            }
        }
    }

    // ---- LDS-write half 1 (vmcnt(0) already satisfied), barrier, compute ----
#pragma unroll
    for (int it = 0; it < 2; ++it) {
        int lin = it * 512 + tid;
        int row = lin >> 4, c = lin & 15;
        *(float4*)&sA[1][row][c * 8] = ra1[it];
        *(float4*)&sB[1][row][c * 8] = rb1[it];
    }
    __syncthreads();

#pragma unroll 4
    for (int hp = 0; hp < 64; hp += 4) {
        Vn av[2], bv[4], wv;
        wv.f4 = *(const float4*)&sW[64 + hp];
#pragma unroll
        for (int i = 0; i < 2; ++i) av[i].f4 = *(const float4*)&sA[1][ty + 32 * i][hp * 2];
#pragma unroll
        for (int j = 0; j < 4; ++j) bv[j].f4 = *(const float4*)&sB[1][tx + 16 * j][hp * 2];
#pragma unroll
        for (int k = 0; k < 4; ++k) {
#pragma unroll
            for (int i = 0; i < 2; ++i) {
#pragma unroll
                for (int j = 0; j < 4; ++j) {
                    h2 s = av[i].h[k] + bv[j].h[k];
                    s = __builtin_elementwise_max(s, z);
                    acc[i][j] = __builtin_amdgcn_fdot2(s, wv.h[k], acc[i][j], false);
                }
            }
        }
    }

    const float bb = b2[0];
#pragma unroll
    for (int i = 0; i < 2; ++i) {
#pragma unroll
        for (int j = 0; j < 4; ++j) {
            float x = acc[i][j] + bb;
            out[(n0 + ty + 32 * i) * M_ + (m0 + tx + 16 * j)] =
                1.0f / (1.0f + __expf(-x));
        }
    }
}

extern "C" void kernel_launch(void* const* d_in, const int* in_sizes, int n_in,
                              void* d_out, int out_size, void* d_ws, size_t ws_size,
                              hipStream_t stream) {
    const float* X  = (const float*)d_in[0];
    const int*   V  = (const int*)d_in[1];
    const int*   E  = (const int*)d_in[2];
    const float* W1 = (const float*)d_in[3];
    const float* b1 = (const float*)d_in[4];
    const float* W2 = (const float*)d_in[5];
    const float* b2 = (const float*)d_in[6];
    float* out = (float*)d_out;

    char* ws = (char*)d_ws;
    _Float16* hx  = (_Float16*)(ws);             // N*H fp16 = 512 KB
    _Float16* heb = (_Float16*)(ws + 524288);    // M*H fp16 = 512 KB

    gemm_kernel<<<256, 512, 0, stream>>>(X, V, E, W1, b1, hx, heb);

    dim3 bgrid(M_ / 64, N_ / 64);
    big_kernel<<<bgrid, 512, 0, stream>>>(hx, heb, W2, b2, out);
}

// Round 8
// 101.136 us; speedup vs baseline: 1.0513x; 1.0513x over previous
//
#include <hip/hip_runtime.h>

#define N_ 1024
#define M_ 1024
#define D_ 128
#define NNZ_ 32768
#define H_ 256

typedef _Float16 h2 __attribute__((ext_vector_type(2)));

// ---- K1: 256 blocks x 512 threads (1 block/CU, 2 waves/SIMD).
// Stage A (B0->B1): waves 0-3: hx rows [4b,4b+4) = X @ W1[:D]  (reg-resident)
//                   waves 4-7: E-scan -> LDS buckets (V loaded only on hit)
// Stage B (B1->B2): waves 0-3 store hx; ALL 512 threads build segment sums
//                   (one (row,d) pair per thread).
// Stage C (B2-> ) : ALL 512 threads heb GEMM (rows split 2/2 across halves).
// All __syncthreads convergent. EXACT round-6 code (best: 101.5 us).
// Closed paths (measured): round-1 4x4/256t K2 retile (+4 us, occupancy);
// round-3 cooperative fusion (+88 us, grid.sync stall); round-7 K2
// split-stage dbuf + K1 unroll-8 scan (+4.8 us, VGPR/I-cache pressure).
__global__ __launch_bounds__(512) void gemm_kernel(
        const float* __restrict__ X, const int* __restrict__ V,
        const int* __restrict__ E, const float* __restrict__ W1,
        const float* __restrict__ b1,
        _Float16* __restrict__ hx, _Float16* __restrict__ heb) {
    __shared__ float sA[8][128];       // rows 0-3: X rows; rows 4-7: segment sums
    __shared__ int s_bkt[4][128];      // bucket (cap 128; counts ~Poisson(32))
    __shared__ int s_cnt[4];
    const int t = threadIdx.x;
    const int b = blockIdx.x;
    const int row0 = b * 4;
    const int m0 = b * 4;
    const int u = t & 255;

    if (t < 128)
        ((float4*)&sA[0][0])[t] = ((const float4*)(X + row0 * D_))[t];
    if (t >= 256 && t < 260) s_cnt[t - 256] = 0;
    __syncthreads();   // B0

    float acc[4];
#pragma unroll
    for (int r = 0; r < 4; ++r) acc[r] = 0.f;

    // ---------- stage A: top GEMM || bottom E-scan ----------
    if (t < 256) {
        const float* __restrict__ Wa = W1;
        for (int dd = 0; dd < D_; dd += 4) {
            float w0 = Wa[(dd + 0) * H_ + t];
            float w1 = Wa[(dd + 1) * H_ + t];
            float w2 = Wa[(dd + 2) * H_ + t];
            float w3 = Wa[(dd + 3) * H_ + t];
#pragma unroll
            for (int r = 0; r < 4; ++r) {
                float4 a = *(const float4*)&sA[r][dd];
                acc[r] = fmaf(a.x, w0, acc[r]);
                acc[r] = fmaf(a.y, w1, acc[r]);
                acc[r] = fmaf(a.z, w2, acc[r]);
                acc[r] = fmaf(a.w, w3, acc[r]);
            }
        }
    } else {
        const int4* E4 = (const int4*)E;
        const int4* V4 = (const int4*)V;
#pragma unroll 4
        for (int it = 0; it < NNZ_ / 4 / 256; ++it) {   // 32 iters
            int idx = it * 256 + u;
            int4 e4 = E4[idx];
            unsigned r0 = (unsigned)(e4.x - m0);
            unsigned r1 = (unsigned)(e4.y - m0);
            unsigned r2 = (unsigned)(e4.z - m0);
            unsigned r3 = (unsigned)(e4.w - m0);
            if ((r0 < 4u) | (r1 < 4u) | (r2 < 4u) | (r3 < 4u)) {
                int4 v4 = V4[idx];
                if (r0 < 4u) { int s = atomicAdd(&s_cnt[r0], 1); s_bkt[r0][s & 127] = v4.x; }
                if (r1 < 4u) { int s = atomicAdd(&s_cnt[r1], 1); s_bkt[r1][s & 127] = v4.y; }
                if (r2 < 4u) { int s = atomicAdd(&s_cnt[r2], 1); s_bkt[r2][s & 127] = v4.z; }
                if (r3 < 4u) { int s = atomicAdd(&s_cnt[r3], 1); s_bkt[r3][s & 127] = v4.w; }
            }
        }
    }
    __syncthreads();   // B1: buckets complete

    // ---------- stage B: hx store, then all-thread segment sums ----------
    if (t < 256) {
#pragma unroll
        for (int r = 0; r < 4; ++r)
            hx[(row0 + r) * H_ + t] = (_Float16)acc[r];
    }
    {
        const int d = t & 127;
        const int r = t >> 7;          // 0..3 — one (row, d) per thread
        const int cnt = min(s_cnt[r], 128);
        float s = 0.f;
        int i = 0;
        for (; i + 8 <= cnt; i += 8) {  // 8 outstanding loads (latency-bound)
            int v0 = s_bkt[r][i],     v1 = s_bkt[r][i + 1];
            int v2 = s_bkt[r][i + 2], v3 = s_bkt[r][i + 3];
            int v4 = s_bkt[r][i + 4], v5 = s_bkt[r][i + 5];
            int v6 = s_bkt[r][i + 6], v7 = s_bkt[r][i + 7];
            s += X[v0 * D_ + d];
            s += X[v1 * D_ + d];
            s += X[v2 * D_ + d];
            s += X[v3 * D_ + d];
            s += X[v4 * D_ + d];
            s += X[v5 * D_ + d];
            s += X[v6 * D_ + d];
            s += X[v7 * D_ + d];
        }
        for (; i + 4 <= cnt; i += 4) {
            int v0 = s_bkt[r][i],     v1 = s_bkt[r][i + 1];
            int v2 = s_bkt[r][i + 2], v3 = s_bkt[r][i + 3];
            s += X[v0 * D_ + d];
            s += X[v1 * D_ + d];
            s += X[v2 * D_ + d];
            s += X[v3 * D_ + d];
        }
        for (; i < cnt; ++i) s += X[s_bkt[r][i] * D_ + d];
        sA[4 + r][d] = s;
    }
    __syncthreads();   // B2: sums visible

    // ---------- stage C: all-thread heb GEMM (rows split 2/2) ----------
    {
        const int rbase = (t < 256) ? 0 : 2;   // rows rbase, rbase+1
        float acc2[2];
        acc2[0] = 0.f;
        acc2[1] = 0.f;
        const float* __restrict__ Wb = W1 + D_ * H_;
        for (int dd = 0; dd < D_; dd += 4) {
            float w0 = Wb[(dd + 0) * H_ + u];
            float w1 = Wb[(dd + 1) * H_ + u];
            float w2 = Wb[(dd + 2) * H_ + u];
            float w3 = Wb[(dd + 3) * H_ + u];
#pragma unroll
            for (int r = 0; r < 2; ++r) {
                float4 a = *(const float4*)&sA[4 + rbase + r][dd];
                acc2[r] = fmaf(a.x, w0, acc2[r]);
                acc2[r] = fmaf(a.y, w1, acc2[r]);
                acc2[r] = fmaf(a.z, w2, acc2[r]);
                acc2[r] = fmaf(a.w, w3, acc2[r]);
            }
        }
        const float bias = b1[u];
#pragma unroll
        for (int r = 0; r < 2; ++r) {
            float inv = 1.0f / fmaxf((float)s_cnt[rbase + r], 1.0f);
            heb[(m0 + rbase + r) * H_ + u] = (_Float16)(acc2[r] * inv + bias);
        }
    }
}

// ---- K2: out[n,m] = sigmoid(b2 + sum_h relu(hx[n,h]+heb[m,h]) * W2[h])
// 64x64 tile / block, 512 threads (2 waves/SIMD), 2x4 per thread, full H=256
// in LDS fp16. Inner loop VALU-bound at 3 instr / 2 h, near the 5.1 us
// packed-VALU floor. EXACT round-6 code.
__global__ __launch_bounds__(512) void big_kernel(
        const _Float16* __restrict__ hx, const _Float16* __restrict__ heb,
        const float* __restrict__ W2, const float* __restrict__ b2,
        float* __restrict__ out) {
    __shared__ _Float16 sA[64][264];   // 264 halves = 528 B row (16B-aligned, shifted)
    __shared__ _Float16 sB[64][264];
    __shared__ h2 sW[H_ / 2];

    const int tid = threadIdx.x;
    const int tx = tid & 15;          // m
    const int ty = tid >> 4;          // n, 0..31
    const int n0 = blockIdx.y * 64;
    const int m0 = blockIdx.x * 64;

    if (tid < H_ / 2) {
        h2 w;
        w.x = (_Float16)W2[2 * tid];
        w.y = (_Float16)W2[2 * tid + 1];
        sW[tid] = w;
    }

    {
        const float4* A4 = (const float4*)hx;   // 32 float4 per 256-half row
        const float4* B4 = (const float4*)heb;
#pragma unroll
        for (int it = 0; it < 4; ++it) {
            int lin = it * 512 + tid;
            int row = lin >> 5;
            int c = lin & 31;
            *(float4*)&sA[row][c * 8] = A4[(n0 + row) * 32 + c];
            *(float4*)&sB[row][c * 8] = B4[(m0 + row) * 32 + c];
        }
    }
    __syncthreads();

    float acc[2][4];
#pragma unroll
    for (int i = 0; i < 2; ++i)
#pragma unroll
        for (int j = 0; j < 4; ++j) acc[i][j] = 0.f;

    union Vn { float4 f4; h2 h[4]; };
    const h2 z = {(_Float16)0.f, (_Float16)0.f};

#pragma unroll 4
    for (int hp = 0; hp < H_ / 2; hp += 4) {
        Vn av[2], bv[4], wv;
        wv.f4 = *(const float4*)&sW[hp];
#pragma unroll
        for (int i = 0; i < 2; ++i) av[i].f4 = *(const float4*)&sA[ty + 32 * i][hp * 2];
#pragma unroll
        for (int j = 0; j < 4; ++j) bv[j].f4 = *(const float4*)&sB[tx + 16 * j][hp * 2];
#pragma unroll
        for (int k = 0; k < 4; ++k) {
#pragma unroll
            for (int i = 0; i < 2; ++i) {
#pragma unroll
                for (int j = 0; j < 4; ++j) {
                    h2 s = av[i].h[k] + bv[j].h[k];
                    s = __builtin_elementwise_max(s, z);
                    acc[i][j] = __builtin_amdgcn_fdot2(s, wv.h[k], acc[i][j], false);
                }
            }
        }
    }

    const float bb = b2[0];
#pragma unroll
    for (int i = 0; i < 2; ++i) {
#pragma unroll
        for (int j = 0; j < 4; ++j) {
            float x = acc[i][j] + bb;
            out[(n0 + ty + 32 * i) * M_ + (m0 + tx + 16 * j)] =
                1.0f / (1.0f + __expf(-x));
        }
    }
}

extern "C" void kernel_launch(void* const* d_in, const int* in_sizes, int n_in,
                              void* d_out, int out_size, void* d_ws, size_t ws_size,
                              hipStream_t stream) {
    const float* X  = (const float*)d_in[0];
    const int*   V  = (const int*)d_in[1];
    const int*   E  = (const int*)d_in[2];
    const float* W1 = (const float*)d_in[3];
    const float* b1 = (const float*)d_in[4];
    const float* W2 = (const float*)d_in[5];
    const float* b2 = (const float*)d_in[6];
    float* out = (float*)d_out;

    char* ws = (char*)d_ws;
    _Float16* hx  = (_Float16*)(ws);             // N*H fp16 = 512 KB
    _Float16* heb = (_Float16*)(ws + 524288);    // M*H fp16 = 512 KB

    gemm_kernel<<<256, 512, 0, stream>>>(X, V, E, W1, b1, hx, heb);

    dim3 bgrid(M_ / 64, N_ / 64);
    big_kernel<<<bgrid, 512, 0, stream>>>(hx, heb, W2, b2, out);
}